// Round 8
// baseline (319.751 us; speedup 1.0000x reference)
//
#include <hip/hip_runtime.h>
#include <math.h>

#define T_DIM 16384
#define A_DIM 128
#define K_DIM 128
#define N_STEPS 16
#define E_DIM 126
#define NSEQ 4

// tiles: 16 atoms x 256 t -> 8 atiles x 64 ttiles = 512 tiles/seq
#define ATI 16
#define TT 256
#define NTT 64
#define NPT 512
#define INC_B 16     // inc blocks per seq: (atile 0..7) x (ttile parity 0..1)
#define RS_LEN 383   // staged res window: TT + K - 1

// order-preserving pack: bigger u64 == (bigger value, then smaller flat idx).
// Never 0 for finite fm values -> 0 is the "empty mailbox" sentinel.
__device__ inline unsigned long long pack_vi(float v, int fi) {
    unsigned int b = __float_as_uint(v);
    b = (b & 0x80000000u) ? ~b : (b | 0x80000000u);
    return ((unsigned long long)b << 32) | (unsigned int)(~fi);
}
__device__ inline void unpack_vi(unsigned long long p, float* v, int* fi) {
    unsigned int lo = (unsigned int)(p & 0xffffffffu);
    unsigned int b = (unsigned int)(p >> 32);
    unsigned int fb = (b & 0x80000000u) ? (b & 0x7fffffffu) : ~b;
    *v = __uint_as_float(fb);
    *fi = (int)(~lo);
}

// ---------------------------------------------------------------------------
// blocks 0..127: d_unit rows; 128..383: res init; 384: zero cnt + mailboxes
__global__ __launch_bounds__(256) void k_prep(
    const float* __restrict__ d, const float* __restrict__ a,
    const float* __restrict__ b, float* __restrict__ du,
    float* __restrict__ res, int* __restrict__ cnt,
    unsigned long long* __restrict__ slots) {
    int blk = blockIdx.x, tid = threadIdx.x;
    if (blk < 128) {
        __shared__ float s[128];
        float v = 0.0f;
        if (tid < 128) { v = d[blk * K_DIM + tid]; s[tid] = v * v; }
        __syncthreads();
        for (int off = 64; off > 0; off >>= 1) {
            if (tid < off) s[tid] += s[tid + off];
            __syncthreads();
        }
        if (tid < 128) du[blk * K_DIM + tid] = v / (sqrtf(s[0]) + 1e-8f);
    } else if (blk < 384) {
        int i = (blk - 128) * 256 + tid;      // 0..65535
        res[i] = (i < 2 * T_DIM) ? a[i] : b[i - 2 * T_DIM];
    } else {
        if (tid < NSEQ) cnt[tid] = 0;
        for (int i = tid; i < (N_STEPS - 1) * NSEQ * INC_B; i += 256) slots[i] = 0ULL;
    }
}

// ---------------------------------------------------------------------------
// 16a x 256t tile:
//  - each wave: 64 consecutive t (lane = t, stride-1) x ALL 16 atoms
//  - per k: ONE conflict-free ds_read_b32 feeds 16 FMAs
//  - du via wave-uniform scalar loads (SMEM pipe; a_base is blockIdx-derived)
//  - argmax: per-wave shfl butterfly, 4-entry LDS combine.
// History (steps 1..nh) replayed onto the staged window with explicit
// mul-then-sub (np order). Per-acc FMA chain = k ascending -> bit-identical.
__device__ inline unsigned long long tile_fast(
    const float* __restrict__ res, const float* __restrict__ du,
    int seq, int a_base, int t0, int tid,
    float* res_sh, unsigned long long* red4,
    const float* val_h, const int* ti_h, const int* ai_h, int nh) {

    const float* resS = res + seq * T_DIM;
    for (int i = tid; i < RS_LEN; i += 256) {
        int t = t0 + i - K_DIM / 2;
        float v = 0.0f;
        if (t >= 0 && t < T_DIM) {
            v = resS[t];
            for (int s = 0; s < nh; s++) {
                int dk = t - (ti_h[s] - K_DIM / 2);
                if (dk >= 0 && dk < K_DIM)
                    v = __fsub_rn(v, __fmul_rn(val_h[s], du[ai_h[s] * K_DIM + dk]));
            }
        }
        res_sh[i] = v;
    }
    __syncthreads();

    int wpos = tid;                       // lane t-offset within tile: wave*64+lane
    const float* duP = du + a_base * K_DIM;   // wave-uniform base -> s_load

    float acc[ATI];
    #pragma unroll
    for (int i = 0; i < ATI; i++) acc[i] = 0.0f;

    #pragma unroll 4
    for (int k = 0; k < K_DIM; k++) {
        float rv = res_sh[wpos + k];      // stride-1 across lanes: conflict-free
        #pragma unroll
        for (int i = 0; i < ATI; i++)
            acc[i] = fmaf(duP[i * K_DIM + k], rv, acc[i]);
    }

    // per-thread argmax over 16 atoms at fixed t (a ascending -> fi ascending)
    int t = t0 + wpos;
    float bv = acc[0];
    int bi = a_base * T_DIM + t;
    #pragma unroll
    for (int i = 1; i < ATI; i++) {
        if (acc[i] > bv) { bv = acc[i]; bi = (a_base + i) * T_DIM + t; }
    }
    // wave butterfly (lanes have distinct t; ties -> smaller fi)
    #pragma unroll
    for (int off = 32; off > 0; off >>= 1) {
        float v2 = __shfl_down(bv, off);
        int   i2 = __shfl_down(bi, off);
        if (v2 > bv || (v2 == bv && i2 < bi)) { bv = v2; bi = i2; }
    }
    if ((tid & 63) == 0) red4[tid >> 6] = pack_vi(bv, bi);
    __syncthreads();
    if (tid == 0) {
        unsigned long long m = red4[0];
        #pragma unroll
        for (int w = 1; w < 4; w++) if (red4[w] > m) m = red4[w];
        red4[0] = m;
    }
    __syncthreads();
    return red4[0];
}

// ---------------------------------------------------------------------------
// step 0: 512 blocks/seq; last arrival reduces pmax, finalizes step 0 into
// global res/emb and publishes the step-1 dirty window.
__global__ __launch_bounds__(256) void k_step_full(
    float* __restrict__ res, const float* __restrict__ du,
    const float* __restrict__ ae, float* __restrict__ emb,
    unsigned long long* __restrict__ pmax, int* __restrict__ cnt,
    int* __restrict__ dirty0) {

    int seq = blockIdx.y;
    int blk = blockIdx.x;                 // 0..511 = atile*64 + ttile
    int a_base = (blk >> 6) * ATI;
    int t0 = (blk & 63) * TT;
    int tid = threadIdx.x;

    alignas(16) __shared__ float res_sh[RS_LEN + 1];
    __shared__ unsigned long long red4[4];
    __shared__ unsigned long long pm_sh[256];
    __shared__ int last_flag;

    unsigned long long p = tile_fast(res, du, seq, a_base, t0, tid,
                                     res_sh, red4, nullptr, nullptr, nullptr, 0);
    if (tid == 0) {
        pmax[seq * NPT + blk] = p;
        __threadfence();
        last_flag = (atomicAdd(&cnt[seq], 1) == NPT - 1);
    }
    __syncthreads();
    if (!last_flag) return;

    __threadfence();
    {
        unsigned long long m0 = pmax[seq * NPT + tid];
        unsigned long long m1 = pmax[seq * NPT + 256 + tid];
        pm_sh[tid] = m0 > m1 ? m0 : m1;
    }
    __syncthreads();
    for (int off = 128; off > 0; off >>= 1) {
        if (tid < off) { if (pm_sh[tid + off] > pm_sh[tid]) pm_sh[tid] = pm_sh[tid + off]; }
        __syncthreads();
    }
    float value; int fi;
    unpack_vi(pm_sh[0], &value, &fi);
    int ai = fi >> 14;
    int ti = fi & (T_DIM - 1);
    int pos_idx = value > 0.0f ? ti : 0;
    int atom_idx = value > 0.0f ? ai : 0;

    float* e = emb + (seq * N_STEPS + 0) * 128;
    if (tid == 0) {
        e[0] = ((float)pos_idx / (float)(T_DIM - 1)) * 20.0f;
        e[1] = value;
        int nlo = ti - (K_DIM - 1); if (nlo < 0) nlo = 0;
        int nhi = ti + K_DIM;       if (nhi > T_DIM) nhi = T_DIM;
        dirty0[seq * 2 + 0] = nlo;
        dirty0[seq * 2 + 1] = nhi;
    }
    if (tid >= 2 && tid < 2 + E_DIM) e[tid] = ae[atom_idx * E_DIM + tid - 2];
    if (tid >= 128) {
        int k = tid - 128;
        int t = ti + k - K_DIM / 2;
        if (t >= 0 && t < T_DIM) {
            float r = res[seq * T_DIM + t];
            res[seq * T_DIM + t] = __fsub_rn(r, __fmul_rn(value, du[ai * K_DIM + k]));
        }
    }
}

// ---------------------------------------------------------------------------
// persistent steps 1..15. Cross-block traffic = one u64 mailbox per block per
// step. Publish: atomicExch. Poll: RELAXED agent-scope atomic loads (no RMW
// serialization, no fences). The mailbox value is the entire message.
__global__ __launch_bounds__(256) void k_inc(
    float* __restrict__ res, const float* __restrict__ du,
    const float* __restrict__ ae, float* __restrict__ emb,
    const unsigned long long* __restrict__ pmax,
    unsigned long long* __restrict__ slots, const int* __restrict__ dirty0) {

    int seq = blockIdx.y;
    int blk = blockIdx.x;                 // 0..15
    int atile = blk >> 1;
    int par = blk & 1;
    int a_base = atile * ATI;
    int tid = threadIdx.x;

    alignas(16) __shared__ float res_sh[RS_LEN + 1];
    __shared__ unsigned long long red4[4];
    __shared__ unsigned long long tmax[32];    // owned ttiles: par, par+2, ...
    __shared__ unsigned long long poll_sh[INC_B];
    __shared__ float val_h[N_STEPS - 1];
    __shared__ int   ti_h[N_STEPS - 1];
    __shared__ int   ai_h[N_STEPS - 1];
    __shared__ int   lo_sh, hi_sh;

    if (tid < 32) tmax[tid] = pmax[seq * NPT + atile * NTT + par + 2 * tid];
    int lo = dirty0[seq * 2 + 0];
    int hi = dirty0[seq * 2 + 1];
    __syncthreads();

    for (int step = 1; step < N_STEPS; step++) {
        int T0 = lo >> 8;
        int tt = ((T0 & 1) == par) ? T0 : T0 + 1;   // my-parity candidate
        bool valid = (tt < NTT) && (tt * TT < hi);  // overlaps dirty window?

        if (valid) {
            unsigned long long p = tile_fast(res, du, seq, a_base, tt * TT,
                                             tid, res_sh, red4,
                                             val_h, ti_h, ai_h, step - 1);
            if (tid == 0) tmax[(tt - par) >> 1] = p;
        }
        if (tid == 0) {
            unsigned long long m = tmax[0];
            for (int j = 1; j < 32; j++) if (tmax[j] > m) m = tmax[j];
            atomicExch(&slots[((step - 1) * NSEQ + seq) * INC_B + blk], m);
        }
        if (tid < INC_B) {
            const unsigned long long* sp =
                &slots[((step - 1) * NSEQ + seq) * INC_B + tid];
            unsigned long long v = __hip_atomic_load(sp, __ATOMIC_RELAXED,
                                                     __HIP_MEMORY_SCOPE_AGENT);
            while (v == 0ULL) {
                __builtin_amdgcn_s_sleep(1);
                v = __hip_atomic_load(sp, __ATOMIC_RELAXED,
                                      __HIP_MEMORY_SCOPE_AGENT);
            }
            poll_sh[tid] = v;
        }
        __syncthreads();
        if (tid == 0) {
            unsigned long long w = poll_sh[0];
            for (int j = 1; j < INC_B; j++) if (poll_sh[j] > w) w = poll_sh[j];
            float value; int fi;
            unpack_vi(w, &value, &fi);
            int ti = fi & (T_DIM - 1);
            val_h[step - 1] = value;
            ti_h[step - 1] = ti;
            ai_h[step - 1] = fi >> 14;
            int nlo = ti - (K_DIM - 1); if (nlo < 0) nlo = 0;
            int nhi = ti + K_DIM;       if (nhi > T_DIM) nhi = T_DIM;
            lo_sh = nlo; hi_sh = nhi;
        }
        __syncthreads();

        if (blk == 0) {   // emb row for this step
            float value = val_h[step - 1];
            int ti = ti_h[step - 1], ai = ai_h[step - 1];
            int pos_idx = value > 0.0f ? ti : 0;
            int atom_idx = value > 0.0f ? ai : 0;
            float* e = emb + (seq * N_STEPS + step) * 128;
            if (tid == 0) {
                e[0] = ((float)pos_idx / (float)(T_DIM - 1)) * 20.0f;
                e[1] = value;
            }
            if (tid >= 2 && tid < 128) e[tid] = ae[atom_idx * E_DIM + tid - 2];
        }
        lo = lo_sh; hi = hi_sh;
    }

    // write final res (updates 1..15, in step order) so k_tail sees it
    if (blk == 0) {
        __syncthreads();
        for (int s = 0; s < N_STEPS - 1; s++) {
            if (tid < 128) {
                int t = ti_h[s] - K_DIM / 2 + tid;
                if (t >= 0 && t < T_DIM) {
                    float r = res[seq * T_DIM + t];
                    res[seq * T_DIM + t] =
                        __fsub_rn(r, __fmul_rn(val_h[s], du[ai_h[s] * K_DIM + tid]));
                }
            }
            __syncthreads();
        }
    }
}

// ---------------------------------------------------------------------------
// norms + ordering + loss; 1 block x 1024 threads
__global__ __launch_bounds__(1024) void k_tail(
    const float* __restrict__ res, const float* __restrict__ emb,
    const float* __restrict__ proj, float* __restrict__ out) {
    int tid = threadIdx.x;
    __shared__ float sh[1024];
    __shared__ float norms[NSEQ];
    __shared__ float keys[NSEQ][N_STEPS];
    __shared__ int   order[NSEQ][N_STEPS];

    {
        int seq = tid >> 8;
        int ln  = tid & 255;
        const float4* r4 = (const float4*)(res + seq * T_DIM);
        float s = 0.0f;
        #pragma unroll
        for (int j = 0; j < 16; j++) {
            float4 v = r4[j * 256 + ln];
            s = fmaf(v.x, v.x, s); s = fmaf(v.y, v.y, s);
            s = fmaf(v.z, v.z, s); s = fmaf(v.w, v.w, s);
        }
        sh[tid] = s;
        __syncthreads();
        for (int off = 128; off > 0; off >>= 1) {
            if (ln < off) sh[tid] += sh[tid + off];
            __syncthreads();
        }
        if (ln == 0) norms[seq] = sqrtf(sh[tid]);
        __syncthreads();
    }
    {
        int pair = tid >> 4;
        int seq = pair >> 4, st = pair & 15;
        int ln = tid & 15;
        const float* e = emb + (seq * N_STEPS + st) * 128 + ln * 8;
        const float* pr = proj + ln * 8;
        float kk = 0.0f;
        #pragma unroll
        for (int dd = 0; dd < 8; dd++) kk = fmaf(e[dd], pr[dd], kk);
        sh[tid] = kk;
        __syncthreads();
        for (int off = 8; off > 0; off >>= 1) {
            if (ln < off) sh[tid] += sh[tid + off];
            __syncthreads();
        }
        if (ln == 0) keys[seq][st] = sh[tid];
        __syncthreads();
    }
    if (tid < NSEQ) {
        int ord[N_STEPS];
        for (int i = 0; i < N_STEPS; i++) ord[i] = i;
        for (int i = 1; i < N_STEPS; i++) {
            int oi = ord[i];
            float kv = keys[tid][oi];
            int j = i - 1;
            while (j >= 0 && keys[tid][ord[j]] > kv) { ord[j + 1] = ord[j]; j--; }
            ord[j + 1] = oi;
        }
        for (int i = 0; i < N_STEPS; i++) order[tid][i] = ord[i];
    }
    __syncthreads();
    float s = 0.0f;
    #pragma unroll
    for (int t = 0; t < 4; t++) {
        int idx = tid + t * 1024;
        int b  = idx >> 11;
        int st = (idx >> 7) & 15;
        int dd = idx & 127;
        float va = emb[((b    ) * N_STEPS + order[b    ][st]) * 128 + dd];
        float vb = emb[((2 + b) * N_STEPS + order[2 + b][st]) * 128 + dd];
        float df = va - vb;
        s = fmaf(df, df, s);
    }
    sh[tid] = s;
    __syncthreads();
    for (int off = 512; off > 0; off >>= 1) {
        if (tid < off) sh[tid] += sh[tid + off];
        __syncthreads();
    }
    if (tid == 0) {
        float mse = sh[0] / 4096.0f;
        float mad = 0.5f * (fabsf(norms[0] - norms[2]) + fabsf(norms[1] - norms[3]));
        out[0] = mse + mad;
    }
}

// ---------------------------------------------------------------------------
extern "C" void kernel_launch(void* const* d_in, const int* in_sizes, int n_in,
                              void* d_out, int out_size, void* d_ws, size_t ws_size,
                              hipStream_t stream) {
    const float* a    = (const float*)d_in[0];
    const float* b    = (const float*)d_in[1];
    const float* d    = (const float*)d_in[2];
    const float* ae   = (const float*)d_in[3];
    const float* proj = (const float*)d_in[4];
    float* out = (float*)d_out;

    float* ws  = (float*)d_ws;
    float* res = ws;                              // 65536 f
    float* du  = res + NSEQ * T_DIM;              // 16384 f
    float* emb = du + A_DIM * K_DIM;              // 8192 f
    unsigned long long* pmax  = (unsigned long long*)(emb + NSEQ * N_STEPS * 128); // 2048 u64
    unsigned long long* slots = pmax + NSEQ * NPT;                                 // 960 u64
    int* cnt    = (int*)(slots + (N_STEPS - 1) * NSEQ * INC_B);
    int* dirty0 = cnt + NSEQ;                     // 8 ints

    k_prep<<<385, 256, 0, stream>>>(d, a, b, du, res, cnt, slots);

    dim3 gfull(NPT, NSEQ);
    k_step_full<<<gfull, 256, 0, stream>>>(res, du, ae, emb, pmax, cnt, dirty0);

    dim3 ginc(INC_B, NSEQ);
    k_inc<<<ginc, 256, 0, stream>>>(res, du, ae, emb, pmax, slots, dirty0);

    k_tail<<<1, 1024, 0, stream>>>(res, emb, proj, out);
}

// Round 9
// 277.765 us; speedup vs baseline: 1.1512x; 1.1512x over previous
//
#include <hip/hip_runtime.h>
#include <math.h>

#define T_DIM 16384
#define A_DIM 128
#define K_DIM 128
#define N_STEPS 16
#define E_DIM 126
#define NSEQ 4

// tiles: 16 atoms x 256 t -> 8 atiles x 64 ttiles = 512 tiles/seq
#define ATI 16
#define TT 256
#define NTT 64
#define NPT 512
#define INC_B 16     // inc blocks per seq: (atile 0..7) x (ttile parity 0..1)
#define RS_LEN 383   // staged res window: TT + K - 1

// order-preserving pack: bigger u64 == (bigger value, then smaller flat idx).
// Never 0 for finite fm values -> 0 is the "empty mailbox" sentinel.
__device__ inline unsigned long long pack_vi(float v, int fi) {
    unsigned int b = __float_as_uint(v);
    b = (b & 0x80000000u) ? ~b : (b | 0x80000000u);
    return ((unsigned long long)b << 32) | (unsigned int)(~fi);
}
__device__ inline void unpack_vi(unsigned long long p, float* v, int* fi) {
    unsigned int lo = (unsigned int)(p & 0xffffffffu);
    unsigned int b = (unsigned int)(p >> 32);
    unsigned int fb = (b & 0x80000000u) ? (b & 0x7fffffffu) : ~b;
    *v = __uint_as_float(fb);
    *fi = (int)(~lo);
}

// ---------------------------------------------------------------------------
// blocks 0..127: d_unit rows; 128..383: res init; 384: zero cnt + mailboxes
__global__ __launch_bounds__(256) void k_prep(
    const float* __restrict__ d, const float* __restrict__ a,
    const float* __restrict__ b, float* __restrict__ du,
    float* __restrict__ res, int* __restrict__ cnt,
    unsigned long long* __restrict__ slots) {
    int blk = blockIdx.x, tid = threadIdx.x;
    if (blk < 128) {
        __shared__ float s[128];
        float v = 0.0f;
        if (tid < 128) { v = d[blk * K_DIM + tid]; s[tid] = v * v; }
        __syncthreads();
        for (int off = 64; off > 0; off >>= 1) {
            if (tid < off) s[tid] += s[tid + off];
            __syncthreads();
        }
        if (tid < 128) du[blk * K_DIM + tid] = v / (sqrtf(s[0]) + 1e-8f);
    } else if (blk < 384) {
        int i = (blk - 128) * 256 + tid;      // 0..65535
        res[i] = (i < 2 * T_DIM) ? a[i] : b[i - 2 * T_DIM];
    } else {
        if (tid < NSEQ) cnt[tid] = 0;
        for (int i = tid; i < (N_STEPS - 1) * NSEQ * INC_B; i += 256) slots[i] = 0ULL;
    }
}

// ---------------------------------------------------------------------------
// 16a x 256t tile, conflict-free operands:
//  - res: stride-1 ds_read_b32 (lane i -> res_sh[... + i])
//  - du:  ds_read_b128 BROADCAST (same address across wave) from 8KB LDS tile
//  - wave mapping: w=tid>>6: atoms a0=(w&1)*8, t half=(w>>1)*128; lane covers
//    t = half*128 + lane + 64*j (j=0,1) -> acc[8][2]
//  - per 4k per wave: 8 du-b128 + 8 res-b32 = 16 LDS instr vs 128 VALU cyc
// History (steps 1..nh) replayed onto the staged window with explicit
// mul-then-sub (np order). Per-acc FMA chain = k ascending -> bit-identical.
__device__ inline unsigned long long tile16_256(
    const float* __restrict__ res, const float* __restrict__ du_g,
    const float* __restrict__ du_sh, int seq, int a_base, int t0, int tid,
    float* res_sh, unsigned long long* red4,
    const float* val_h, const int* ti_h, const int* ai_h, int nh) {

    const float* resS = res + seq * T_DIM;
    for (int i = tid; i < RS_LEN; i += 256) {
        int t = t0 + i - K_DIM / 2;
        float v = 0.0f;
        if (t >= 0 && t < T_DIM) {
            v = resS[t];
            for (int s = 0; s < nh; s++) {
                int dk = t - (ti_h[s] - K_DIM / 2);
                if (dk >= 0 && dk < K_DIM)
                    v = __fsub_rn(v, __fmul_rn(val_h[s], du_g[ai_h[s] * K_DIM + dk]));
            }
        }
        res_sh[i] = v;
    }
    __syncthreads();

    int lane = tid & 63;
    int w = tid >> 6;
    int a0 = (w & 1) * 8;              // wave-uniform
    int half = (w >> 1) * 128;         // wave-uniform
    int tofs = half + lane;
    const float* duS = du_sh + a0 * K_DIM;

    float acc[8][2];
    #pragma unroll
    for (int i = 0; i < 8; i++) { acc[i][0] = 0.0f; acc[i][1] = 0.0f; }

    for (int k = 0; k < K_DIM; k += 4) {
        float4 dq[8];
        #pragma unroll
        for (int i = 0; i < 8; i++)
            dq[i] = *(const float4*)&duS[i * K_DIM + k];   // broadcast b128
        #pragma unroll
        for (int dk = 0; dk < 4; dk++) {
            float r0 = res_sh[tofs + k + dk];              // stride-1 b32
            float r1 = res_sh[tofs + 64 + k + dk];
            #pragma unroll
            for (int i = 0; i < 8; i++) {
                float dv = ((const float*)&dq[i])[dk];
                acc[i][0] = fmaf(dv, r0, acc[i][0]);       // k ascending per acc
                acc[i][1] = fmaf(dv, r1, acc[i][1]);
            }
        }
    }

    // per-thread argmax; scan order = ascending flat index (i outer, j inner)
    float bv = -INFINITY;
    int bi = 0x7fffffff;
    #pragma unroll
    for (int i = 0; i < 8; i++) {
        int a = a_base + a0 + i;
        #pragma unroll
        for (int j = 0; j < 2; j++) {
            int t = t0 + half + lane + 64 * j;
            int fi = a * T_DIM + t;
            float v = acc[i][j];
            if (v > bv || (v == bv && fi < bi)) { bv = v; bi = fi; }
        }
    }
    // wave butterfly
    #pragma unroll
    for (int off = 32; off > 0; off >>= 1) {
        float v2 = __shfl_down(bv, off);
        int   i2 = __shfl_down(bi, off);
        if (v2 > bv || (v2 == bv && i2 < bi)) { bv = v2; bi = i2; }
    }
    if (lane == 0) red4[w] = pack_vi(bv, bi);
    __syncthreads();
    if (tid == 0) {
        unsigned long long m = red4[0];
        #pragma unroll
        for (int ww = 1; ww < 4; ww++) if (red4[ww] > m) m = red4[ww];
        red4[0] = m;
    }
    __syncthreads();
    return red4[0];
}

// ---------------------------------------------------------------------------
// step 0: 512 blocks/seq; last arrival reduces pmax, finalizes step 0 into
// global res/emb and publishes the step-1 dirty window.
__global__ __launch_bounds__(256) void k_step_full(
    float* __restrict__ res, const float* __restrict__ du,
    const float* __restrict__ ae, float* __restrict__ emb,
    unsigned long long* __restrict__ pmax, int* __restrict__ cnt,
    int* __restrict__ dirty0) {

    int seq = blockIdx.y;
    int blk = blockIdx.x;                 // 0..511 = atile*64 + ttile
    int a_base = (blk >> 6) * ATI;
    int t0 = (blk & 63) * TT;
    int tid = threadIdx.x;

    __shared__ float du_sh[ATI * K_DIM];       // 8 KB
    alignas(16) __shared__ float res_sh[RS_LEN + 1];
    __shared__ unsigned long long red4[4];
    __shared__ unsigned long long pm_sh[256];
    __shared__ int last_flag;

    for (int i = tid; i < ATI * K_DIM; i += 256) du_sh[i] = du[a_base * K_DIM + i];
    // tile16_256's post-staging __syncthreads covers du_sh too
    unsigned long long p = tile16_256(res, du, du_sh, seq, a_base, t0, tid,
                                      res_sh, red4, nullptr, nullptr, nullptr, 0);
    if (tid == 0) {
        pmax[seq * NPT + blk] = p;
        __threadfence();
        last_flag = (atomicAdd(&cnt[seq], 1) == NPT - 1);
    }
    __syncthreads();
    if (!last_flag) return;

    __threadfence();
    {
        unsigned long long m0 = pmax[seq * NPT + tid];
        unsigned long long m1 = pmax[seq * NPT + 256 + tid];
        pm_sh[tid] = m0 > m1 ? m0 : m1;
    }
    __syncthreads();
    for (int off = 128; off > 0; off >>= 1) {
        if (tid < off) { if (pm_sh[tid + off] > pm_sh[tid]) pm_sh[tid] = pm_sh[tid + off]; }
        __syncthreads();
    }
    float value; int fi;
    unpack_vi(pm_sh[0], &value, &fi);
    int ai = fi >> 14;
    int ti = fi & (T_DIM - 1);
    int pos_idx = value > 0.0f ? ti : 0;
    int atom_idx = value > 0.0f ? ai : 0;

    float* e = emb + (seq * N_STEPS + 0) * 128;
    if (tid == 0) {
        e[0] = ((float)pos_idx / (float)(T_DIM - 1)) * 20.0f;
        e[1] = value;
        int nlo = ti - (K_DIM - 1); if (nlo < 0) nlo = 0;
        int nhi = ti + K_DIM;       if (nhi > T_DIM) nhi = T_DIM;
        dirty0[seq * 2 + 0] = nlo;
        dirty0[seq * 2 + 1] = nhi;
    }
    if (tid >= 2 && tid < 2 + E_DIM) e[tid] = ae[atom_idx * E_DIM + tid - 2];
    if (tid >= 128) {
        int k = tid - 128;
        int t = ti + k - K_DIM / 2;
        if (t >= 0 && t < T_DIM) {
            float r = res[seq * T_DIM + t];
            res[seq * T_DIM + t] = __fsub_rn(r, __fmul_rn(value, du[ai * K_DIM + k]));
        }
    }
}

// ---------------------------------------------------------------------------
// persistent steps 1..15. Cross-block traffic = one u64 mailbox per block per
// step. Publish: atomicExch. Poll: RELAXED agent-scope atomic loads (no RMW
// serialization, no fences). The mailbox value is the entire message.
__global__ __launch_bounds__(256) void k_inc(
    float* __restrict__ res, const float* __restrict__ du,
    const float* __restrict__ ae, float* __restrict__ emb,
    const unsigned long long* __restrict__ pmax,
    unsigned long long* __restrict__ slots, const int* __restrict__ dirty0) {

    int seq = blockIdx.y;
    int blk = blockIdx.x;                 // 0..15
    int atile = blk >> 1;
    int par = blk & 1;
    int a_base = atile * ATI;
    int tid = threadIdx.x;

    __shared__ float du_sh[ATI * K_DIM];       // 8 KB, staged once
    alignas(16) __shared__ float res_sh[RS_LEN + 1];
    __shared__ unsigned long long red4[4];
    __shared__ unsigned long long tmax[32];    // owned ttiles: par, par+2, ...
    __shared__ unsigned long long poll_sh[INC_B];
    __shared__ float val_h[N_STEPS - 1];
    __shared__ int   ti_h[N_STEPS - 1];
    __shared__ int   ai_h[N_STEPS - 1];
    __shared__ int   lo_sh, hi_sh;

    for (int i = tid; i < ATI * K_DIM; i += 256) du_sh[i] = du[a_base * K_DIM + i];
    if (tid < 32) tmax[tid] = pmax[seq * NPT + atile * NTT + par + 2 * tid];
    int lo = dirty0[seq * 2 + 0];
    int hi = dirty0[seq * 2 + 1];
    __syncthreads();

    for (int step = 1; step < N_STEPS; step++) {
        int T0 = lo >> 8;
        int tt = ((T0 & 1) == par) ? T0 : T0 + 1;   // my-parity candidate
        bool valid = (tt < NTT) && (tt * TT < hi);  // overlaps dirty window?

        if (valid) {
            unsigned long long p = tile16_256(res, du, du_sh, seq, a_base,
                                              tt * TT, tid, res_sh, red4,
                                              val_h, ti_h, ai_h, step - 1);
            if (tid == 0) tmax[(tt - par) >> 1] = p;
        }
        if (tid == 0) {
            unsigned long long m = tmax[0];
            for (int j = 1; j < 32; j++) if (tmax[j] > m) m = tmax[j];
            atomicExch(&slots[((step - 1) * NSEQ + seq) * INC_B + blk], m);
        }
        if (tid < INC_B) {
            const unsigned long long* sp =
                &slots[((step - 1) * NSEQ + seq) * INC_B + tid];
            unsigned long long v = __hip_atomic_load(sp, __ATOMIC_RELAXED,
                                                     __HIP_MEMORY_SCOPE_AGENT);
            while (v == 0ULL) {
                __builtin_amdgcn_s_sleep(1);
                v = __hip_atomic_load(sp, __ATOMIC_RELAXED,
                                      __HIP_MEMORY_SCOPE_AGENT);
            }
            poll_sh[tid] = v;
        }
        __syncthreads();
        if (tid == 0) {
            unsigned long long w = poll_sh[0];
            for (int j = 1; j < INC_B; j++) if (poll_sh[j] > w) w = poll_sh[j];
            float value; int fi;
            unpack_vi(w, &value, &fi);
            int ti = fi & (T_DIM - 1);
            val_h[step - 1] = value;
            ti_h[step - 1] = ti;
            ai_h[step - 1] = fi >> 14;
            int nlo = ti - (K_DIM - 1); if (nlo < 0) nlo = 0;
            int nhi = ti + K_DIM;       if (nhi > T_DIM) nhi = T_DIM;
            lo_sh = nlo; hi_sh = nhi;
        }
        __syncthreads();

        if (blk == 0) {   // emb row for this step
            float value = val_h[step - 1];
            int ti = ti_h[step - 1], ai = ai_h[step - 1];
            int pos_idx = value > 0.0f ? ti : 0;
            int atom_idx = value > 0.0f ? ai : 0;
            float* e = emb + (seq * N_STEPS + step) * 128;
            if (tid == 0) {
                e[0] = ((float)pos_idx / (float)(T_DIM - 1)) * 20.0f;
                e[1] = value;
            }
            if (tid >= 2 && tid < 128) e[tid] = ae[atom_idx * E_DIM + tid - 2];
        }
        lo = lo_sh; hi = hi_sh;
    }

    // write final res (updates 1..15, in step order) so k_tail sees it
    if (blk == 0) {
        __syncthreads();
        for (int s = 0; s < N_STEPS - 1; s++) {
            if (tid < 128) {
                int t = ti_h[s] - K_DIM / 2 + tid;
                if (t >= 0 && t < T_DIM) {
                    float r = res[seq * T_DIM + t];
                    res[seq * T_DIM + t] =
                        __fsub_rn(r, __fmul_rn(val_h[s], du[ai_h[s] * K_DIM + tid]));
                }
            }
            __syncthreads();
        }
    }
}

// ---------------------------------------------------------------------------
// norms + ordering + loss; 1 block x 1024 threads
__global__ __launch_bounds__(1024) void k_tail(
    const float* __restrict__ res, const float* __restrict__ emb,
    const float* __restrict__ proj, float* __restrict__ out) {
    int tid = threadIdx.x;
    __shared__ float sh[1024];
    __shared__ float norms[NSEQ];
    __shared__ float keys[NSEQ][N_STEPS];
    __shared__ int   order[NSEQ][N_STEPS];

    {
        int seq = tid >> 8;
        int ln  = tid & 255;
        const float4* r4 = (const float4*)(res + seq * T_DIM);
        float s = 0.0f;
        #pragma unroll
        for (int j = 0; j < 16; j++) {
            float4 v = r4[j * 256 + ln];
            s = fmaf(v.x, v.x, s); s = fmaf(v.y, v.y, s);
            s = fmaf(v.z, v.z, s); s = fmaf(v.w, v.w, s);
        }
        sh[tid] = s;
        __syncthreads();
        for (int off = 128; off > 0; off >>= 1) {
            if (ln < off) sh[tid] += sh[tid + off];
            __syncthreads();
        }
        if (ln == 0) norms[seq] = sqrtf(sh[tid]);
        __syncthreads();
    }
    {
        int pair = tid >> 4;
        int seq = pair >> 4, st = pair & 15;
        int ln = tid & 15;
        const float* e = emb + (seq * N_STEPS + st) * 128 + ln * 8;
        const float* pr = proj + ln * 8;
        float kk = 0.0f;
        #pragma unroll
        for (int dd = 0; dd < 8; dd++) kk = fmaf(e[dd], pr[dd], kk);
        sh[tid] = kk;
        __syncthreads();
        for (int off = 8; off > 0; off >>= 1) {
            if (ln < off) sh[tid] += sh[tid + off];
            __syncthreads();
        }
        if (ln == 0) keys[seq][st] = sh[tid];
        __syncthreads();
    }
    if (tid < NSEQ) {
        int ord[N_STEPS];
        for (int i = 0; i < N_STEPS; i++) ord[i] = i;
        for (int i = 1; i < N_STEPS; i++) {
            int oi = ord[i];
            float kv = keys[tid][oi];
            int j = i - 1;
            while (j >= 0 && keys[tid][ord[j]] > kv) { ord[j + 1] = ord[j]; j--; }
            ord[j + 1] = oi;
        }
        for (int i = 0; i < N_STEPS; i++) order[tid][i] = ord[i];
    }
    __syncthreads();
    float s = 0.0f;
    #pragma unroll
    for (int t = 0; t < 4; t++) {
        int idx = tid + t * 1024;
        int b  = idx >> 11;
        int st = (idx >> 7) & 15;
        int dd = idx & 127;
        float va = emb[((b    ) * N_STEPS + order[b    ][st]) * 128 + dd];
        float vb = emb[((2 + b) * N_STEPS + order[2 + b][st]) * 128 + dd];
        float df = va - vb;
        s = fmaf(df, df, s);
    }
    sh[tid] = s;
    __syncthreads();
    for (int off = 512; off > 0; off >>= 1) {
        if (tid < off) sh[tid] += sh[tid + off];
        __syncthreads();
    }
    if (tid == 0) {
        float mse = sh[0] / 4096.0f;
        float mad = 0.5f * (fabsf(norms[0] - norms[2]) + fabsf(norms[1] - norms[3]));
        out[0] = mse + mad;
    }
}

// ---------------------------------------------------------------------------
extern "C" void kernel_launch(void* const* d_in, const int* in_sizes, int n_in,
                              void* d_out, int out_size, void* d_ws, size_t ws_size,
                              hipStream_t stream) {
    const float* a    = (const float*)d_in[0];
    const float* b    = (const float*)d_in[1];
    const float* d    = (const float*)d_in[2];
    const float* ae   = (const float*)d_in[3];
    const float* proj = (const float*)d_in[4];
    float* out = (float*)d_out;

    float* ws  = (float*)d_ws;
    float* res = ws;                              // 65536 f
    float* du  = res + NSEQ * T_DIM;              // 16384 f
    float* emb = du + A_DIM * K_DIM;              // 8192 f
    unsigned long long* pmax  = (unsigned long long*)(emb + NSEQ * N_STEPS * 128); // 2048 u64
    unsigned long long* slots = pmax + NSEQ * NPT;                                 // 960 u64
    int* cnt    = (int*)(slots + (N_STEPS - 1) * NSEQ * INC_B);
    int* dirty0 = cnt + NSEQ;                     // 8 ints

    k_prep<<<385, 256, 0, stream>>>(d, a, b, du, res, cnt, slots);

    dim3 gfull(NPT, NSEQ);
    k_step_full<<<gfull, 256, 0, stream>>>(res, du, ae, emb, pmax, cnt, dirty0);

    dim3 ginc(INC_B, NSEQ);
    k_inc<<<ginc, 256, 0, stream>>>(res, du, ae, emb, pmax, slots, dirty0);

    k_tail<<<1, 1024, 0, stream>>>(res, emb, proj, out);
}

// Round 10
// 243.824 us; speedup vs baseline: 1.3114x; 1.1392x over previous
//
#include <hip/hip_runtime.h>
#include <math.h>

#define T_DIM 16384
#define A_DIM 128
#define K_DIM 128
#define N_STEPS 16
#define E_DIM 126
#define NSEQ 4

// tiles: 16 atoms x 256 t -> 8 atiles x 64 ttiles = 512 tiles/seq
#define ATI 16
#define TT 256
#define NPT 512
#define INC_B 32        // inc blocks/seq: 8 atiles x 2 halves x 2 parities
#define HB 8192         // half length in t
#define RL_LEN 8319     // local residual coverage: [base-64, base+8255)
#define RL_PAD 8608     // PIDX(8323)=8583 max touched; margin
#define SS_LEN 383      // staged window (step_full)
#define SS_PAD 404      // PIDX(387)=399 max touched

#define PIDX(i) ((i) + ((i) >> 5))   // +1 pad per 32: kills 4-dword-per-lane aliasing

// order-preserving pack: bigger u64 == (bigger value, then smaller flat idx).
// Never 0 for finite fm values -> 0 is the "empty mailbox" sentinel.
__device__ inline unsigned long long pack_vi(float v, int fi) {
    unsigned int b = __float_as_uint(v);
    b = (b & 0x80000000u) ? ~b : (b | 0x80000000u);
    return ((unsigned long long)b << 32) | (unsigned int)(~fi);
}
__device__ inline void unpack_vi(unsigned long long p, float* v, int* fi) {
    unsigned int lo = (unsigned int)(p & 0xffffffffu);
    unsigned int b = (unsigned int)(p >> 32);
    unsigned int fb = (b & 0x80000000u) ? (b & 0x7fffffffu) : ~b;
    *v = __uint_as_float(fb);
    *fi = (int)(~lo);
}

// ---------------------------------------------------------------------------
// blocks 0..127: d_unit rows; 128..383: res init; 384: zero cnt + mailboxes
__global__ __launch_bounds__(256) void k_prep(
    const float* __restrict__ d, const float* __restrict__ a,
    const float* __restrict__ b, float* __restrict__ du,
    float* __restrict__ res, int* __restrict__ cnt,
    unsigned long long* __restrict__ slots) {
    int blk = blockIdx.x, tid = threadIdx.x;
    if (blk < 128) {
        __shared__ float s[128];
        float v = 0.0f;
        if (tid < 128) { v = d[blk * K_DIM + tid]; s[tid] = v * v; }
        __syncthreads();
        for (int off = 64; off > 0; off >>= 1) {
            if (tid < off) s[tid] += s[tid + off];
            __syncthreads();
        }
        if (tid < 128) du[blk * K_DIM + tid] = v / (sqrtf(s[0]) + 1e-8f);
    } else if (blk < 384) {
        int i = (blk - 128) * 256 + tid;      // 0..65535
        res[i] = (i < 2 * T_DIM) ? a[i] : b[i - 2 * T_DIM];
    } else {
        if (tid < NSEQ) cnt[tid] = 0;
        for (int i = tid; i < (N_STEPS - 1) * NSEQ * INC_B; i += 256) slots[i] = 0ULL;
    }
}

// ---------------------------------------------------------------------------
// 16a x 256t tile engine. du via wave-uniform s_load float4 (R7-proven);
// res via PADDED scalar b32 sliding window: lane owns t = t_lo + j (4 consec),
// refills 4/quad, zero bank conflicts. Per-acc FMA chain = k ascending, same
// operand order as R7 -> bit-identical fm. Block argmax via shfl + red4.
__device__ inline unsigned long long tile_compute(
    const float* __restrict__ duP, const float* __restrict__ rsh,
    int L0, int a_lo, int t_lo, int tid, unsigned long long* red4) {

    float acc[4][4];
    #pragma unroll
    for (int i = 0; i < 4; i++)
        #pragma unroll
        for (int j = 0; j < 4; j++) acc[i][j] = 0.0f;

    float r[8];
    #pragma unroll
    for (int m = 0; m < 8; m++) r[m] = rsh[PIDX(L0 + m)];

    #pragma unroll 4
    for (int k = 0; k < K_DIM; k += 4) {
        float dA[4][4];
        #pragma unroll
        for (int i = 0; i < 4; i++)
            *(float4*)dA[i] = *(const float4*)(duP + i * K_DIM + k);  // uniform s_load
        #pragma unroll
        for (int dk = 0; dk < 4; dk++) {
            #pragma unroll
            for (int i = 0; i < 4; i++) {
                float s = dA[i][dk];
                #pragma unroll
                for (int j = 0; j < 4; j++)
                    acc[i][j] = fmaf(s, r[j + dk], acc[i][j]);   // k ascending per acc
            }
        }
        r[0] = r[4]; r[1] = r[5]; r[2] = r[6]; r[3] = r[7];
        #pragma unroll
        for (int m = 0; m < 4; m++) r[4 + m] = rsh[PIDX(L0 + k + 8 + m)];  // pad: no conflicts
    }

    float bv = -INFINITY;
    int bi = 0x7fffffff;
    #pragma unroll
    for (int i = 0; i < 4; i++) {          // ascending flat index scan
        int a = a_lo + i;
        #pragma unroll
        for (int j = 0; j < 4; j++) {
            int t = t_lo + j;
            int fi = a * T_DIM + t;
            float v = acc[i][j];
            if (v > bv || (v == bv && fi < bi)) { bv = v; bi = fi; }
        }
    }
    #pragma unroll
    for (int off = 32; off > 0; off >>= 1) {
        float v2 = __shfl_down(bv, off);
        int   i2 = __shfl_down(bi, off);
        if (v2 > bv || (v2 == bv && i2 < bi)) { bv = v2; bi = i2; }
    }
    if ((tid & 63) == 0) red4[tid >> 6] = pack_vi(bv, bi);
    __syncthreads();
    if (tid == 0) {
        unsigned long long m = red4[0];
        #pragma unroll
        for (int w = 1; w < 4; w++) if (red4[w] > m) m = red4[w];
        red4[0] = m;
    }
    __syncthreads();
    return red4[0];
}

// ---------------------------------------------------------------------------
// step 0: 512 blocks/seq; staged padded window; last arrival reduces pmax,
// finalizes step 0 into global res/emb, publishes step-1 dirty window.
__global__ __launch_bounds__(256) void k_step_full(
    float* __restrict__ res, const float* __restrict__ du,
    const float* __restrict__ ae, float* __restrict__ emb,
    unsigned long long* __restrict__ pmax, int* __restrict__ cnt,
    int* __restrict__ dirty0) {

    int seq = blockIdx.y;
    int blk = blockIdx.x;                 // 0..511 = atile*64 + ttile
    int a_base = (blk >> 6) * ATI;
    int t0 = (blk & 63) * TT;
    int tid = threadIdx.x;

    __shared__ float rsh[SS_PAD];
    __shared__ unsigned long long red4[4];
    __shared__ unsigned long long pm_sh[256];
    __shared__ int last_flag;

    const float* resS = res + seq * T_DIM;
    for (int i = tid; i < SS_LEN; i += 256) {
        int t = t0 - 64 + i;
        rsh[PIDX(i)] = (t >= 0 && t < T_DIM) ? resS[t] : 0.0f;
    }
    __syncthreads();

    int tg = tid & 63;
    int ag = __builtin_amdgcn_readfirstlane(tid >> 6);
    unsigned long long p = tile_compute(du + (a_base + ag * 4) * K_DIM, rsh,
                                        4 * tg, a_base + ag * 4, t0 + 4 * tg,
                                        tid, red4);
    if (tid == 0) {
        pmax[seq * NPT + blk] = p;
        __threadfence();
        last_flag = (atomicAdd(&cnt[seq], 1) == NPT - 1);
    }
    __syncthreads();
    if (!last_flag) return;

    __threadfence();
    {
        unsigned long long m0 = pmax[seq * NPT + tid];
        unsigned long long m1 = pmax[seq * NPT + 256 + tid];
        pm_sh[tid] = m0 > m1 ? m0 : m1;
    }
    __syncthreads();
    for (int off = 128; off > 0; off >>= 1) {
        if (tid < off) { if (pm_sh[tid + off] > pm_sh[tid]) pm_sh[tid] = pm_sh[tid + off]; }
        __syncthreads();
    }
    float value; int fi;
    unpack_vi(pm_sh[0], &value, &fi);
    int ai = fi >> 14;
    int ti = fi & (T_DIM - 1);
    int pos_idx = value > 0.0f ? ti : 0;
    int atom_idx = value > 0.0f ? ai : 0;

    float* e = emb + (seq * N_STEPS + 0) * 128;
    if (tid == 0) {
        e[0] = ((float)pos_idx / (float)(T_DIM - 1)) * 20.0f;
        e[1] = value;
        int nlo = ti - (K_DIM - 1); if (nlo < 0) nlo = 0;
        int nhi = ti + K_DIM;       if (nhi > T_DIM) nhi = T_DIM;
        dirty0[seq * 2 + 0] = nlo;
        dirty0[seq * 2 + 1] = nhi;
    }
    if (tid >= 2 && tid < 2 + E_DIM) e[tid] = ae[atom_idx * E_DIM + tid - 2];
    if (tid >= 128) {
        int k = tid - 128;
        int t = ti + k - K_DIM / 2;
        if (t >= 0 && t < T_DIM) {
            float r = res[seq * T_DIM + t];
            res[seq * T_DIM + t] = __fsub_rn(r, __fmul_rn(value, du[ai * K_DIM + k]));
        }
    }
}

// ---------------------------------------------------------------------------
// persistent steps 1..15, LDS-resident residual halves.
// 32 blocks/seq = atile(8) x half(2) x parity(2). Each block keeps its half's
// residual in LDS, applies each winner's update locally (mailbox message IS
// the update), recomputes its dirty tile, publishes its 16 owned tile maxima's
// max. Sync: atomicExch publish + relaxed-poll (proven fence-free protocol).
__global__ __launch_bounds__(256) void k_inc(
    float* __restrict__ res, const float* __restrict__ du,
    const float* __restrict__ ae, float* __restrict__ emb,
    const unsigned long long* __restrict__ pmax,
    unsigned long long* __restrict__ slots, const int* __restrict__ dirty0) {

    int seq = blockIdx.y;
    int blk = blockIdx.x;                 // 0..31
    int atile = blk >> 2;                 // 0..7
    int half = (blk >> 1) & 1;
    int par = blk & 1;
    int a_base = atile * ATI;
    int base = half * HB;
    int tid = threadIdx.x;

    __shared__ float resL[RL_PAD];             // ~34 KB padded local residual
    __shared__ unsigned long long red4[4];
    __shared__ unsigned long long tmax[16];    // owned ttiles: half*32+par+2m
    __shared__ unsigned long long poll_sh[INC_B];
    __shared__ float val_s;
    __shared__ int   ti_s, ai_s, lo_sh, hi_sh;

    // ---- load local residual (post-step-0 global res), zero guards ----
    const float* resG = res + seq * T_DIM;
    for (int i4 = tid * 4; i4 < RL_LEN; i4 += 1024) {
        int t = base - 64 + i4;
        if (t >= 0 && t + 3 < T_DIM && i4 + 3 < RL_LEN) {
            float4 v = *(const float4*)&resG[t];
            resL[PIDX(i4 + 0)] = v.x; resL[PIDX(i4 + 1)] = v.y;
            resL[PIDX(i4 + 2)] = v.z; resL[PIDX(i4 + 3)] = v.w;
        } else {
            for (int m = 0; m < 4 && i4 + m < RL_LEN; m++) {
                int t2 = t + m;
                resL[PIDX(i4 + m)] = (t2 >= 0 && t2 < T_DIM) ? resG[t2] : 0.0f;
            }
        }
    }
    if (tid < 16) {
        int tt = half * 32 + par + 2 * tid;
        tmax[tid] = pmax[seq * NPT + atile * 64 + tt];
    }
    int lo = dirty0[seq * 2 + 0];
    int hi = dirty0[seq * 2 + 1];
    __syncthreads();

    for (int step = 1; step < N_STEPS; step++) {
        // dirty window (<=255 wide) spans ttiles T0, T0+1; mine if par+half match
        int T0 = lo >> 8;
        int cand = -1;
        if (((T0 & 1) == par) && ((T0 >> 5) == half)) cand = T0;
        int T1 = T0 + 1;
        if (T1 < 64 && ((T1 & 1) == par) && ((T1 >> 5) == half) && T1 * TT < hi)
            cand = T1;

        if (cand >= 0) {
            int t0 = cand * TT;
            int tg = tid & 63;
            int ag = __builtin_amdgcn_readfirstlane(tid >> 6);
            unsigned long long p = tile_compute(
                du + (a_base + ag * 4) * K_DIM, resL,
                (t0 - base) + 4 * tg, a_base + ag * 4, t0 + 4 * tg, tid, red4);
            if (tid == 0) tmax[(cand - half * 32 - par) >> 1] = p;
        }
        if (tid == 0) {
            unsigned long long m = tmax[0];
            for (int j = 1; j < 16; j++) if (tmax[j] > m) m = tmax[j];
            atomicExch(&slots[((step - 1) * NSEQ + seq) * INC_B + blk], m);
        }
        if (tid < INC_B) {
            const unsigned long long* sp =
                &slots[((step - 1) * NSEQ + seq) * INC_B + tid];
            unsigned long long v = __hip_atomic_load(sp, __ATOMIC_RELAXED,
                                                     __HIP_MEMORY_SCOPE_AGENT);
            while (v == 0ULL) {
                __builtin_amdgcn_s_sleep(1);
                v = __hip_atomic_load(sp, __ATOMIC_RELAXED,
                                      __HIP_MEMORY_SCOPE_AGENT);
            }
            poll_sh[tid] = v;
        }
        __syncthreads();
        if (tid == 0) {
            unsigned long long w = poll_sh[0];
            for (int j = 1; j < INC_B; j++) if (poll_sh[j] > w) w = poll_sh[j];
            float value; int fi;
            unpack_vi(w, &value, &fi);
            int ti = fi & (T_DIM - 1);
            val_s = value; ti_s = ti; ai_s = fi >> 14;
            int nlo = ti - (K_DIM - 1); if (nlo < 0) nlo = 0;
            int nhi = ti + K_DIM;       if (nhi > T_DIM) nhi = T_DIM;
            lo_sh = nlo; hi_sh = nhi;
        }
        __syncthreads();

        if (blk == 0) {   // emb row for this step
            float value = val_s;
            int ti = ti_s, ai = ai_s;
            int pos_idx = value > 0.0f ? ti : 0;
            int atom_idx = value > 0.0f ? ai : 0;
            float* e = emb + (seq * N_STEPS + step) * 128;
            if (tid == 0) {
                e[0] = ((float)pos_idx / (float)(T_DIM - 1)) * 20.0f;
                e[1] = value;
            }
            if (tid >= 2 && tid < 128) e[tid] = ae[atom_idx * E_DIM + tid - 2];
        }
        // apply winner's update to local residual (mul-then-sub, step order)
        if (tid < 128) {
            int t = ti_s - K_DIM / 2 + tid;
            if (t >= 0 && t < T_DIM) {
                int L = t - base + 64;
                if (L >= 0 && L < RL_LEN) {
                    float r = resL[PIDX(L)];
                    resL[PIDX(L)] = __fsub_rn(r, __fmul_rn(val_s, du[ai_s * K_DIM + tid]));
                }
            }
        }
        __syncthreads();
        lo = lo_sh; hi = hi_sh;
    }

    // final residual write-back (one block per half per seq) for k_tail
    if (atile == 0 && par == 0) {
        float* resW = res + seq * T_DIM + base;
        for (int t = tid; t < HB; t += 256) resW[t] = resL[PIDX(t + 64)];
    }
}

// ---------------------------------------------------------------------------
// norms + ordering + loss; 1 block x 1024 threads
__global__ __launch_bounds__(1024) void k_tail(
    const float* __restrict__ res, const float* __restrict__ emb,
    const float* __restrict__ proj, float* __restrict__ out) {
    int tid = threadIdx.x;
    __shared__ float sh[1024];
    __shared__ float norms[NSEQ];
    __shared__ float keys[NSEQ][N_STEPS];
    __shared__ int   order[NSEQ][N_STEPS];

    {
        int seq = tid >> 8;
        int ln  = tid & 255;
        const float4* r4 = (const float4*)(res + seq * T_DIM);
        float s = 0.0f;
        #pragma unroll
        for (int j = 0; j < 16; j++) {
            float4 v = r4[j * 256 + ln];
            s = fmaf(v.x, v.x, s); s = fmaf(v.y, v.y, s);
            s = fmaf(v.z, v.z, s); s = fmaf(v.w, v.w, s);
        }
        sh[tid] = s;
        __syncthreads();
        for (int off = 128; off > 0; off >>= 1) {
            if (ln < off) sh[tid] += sh[tid + off];
            __syncthreads();
        }
        if (ln == 0) norms[seq] = sqrtf(sh[tid]);
        __syncthreads();
    }
    {
        int pair = tid >> 4;
        int seq = pair >> 4, st = pair & 15;
        int ln = tid & 15;
        const float* e = emb + (seq * N_STEPS + st) * 128 + ln * 8;
        const float* pr = proj + ln * 8;
        float kk = 0.0f;
        #pragma unroll
        for (int dd = 0; dd < 8; dd++) kk = fmaf(e[dd], pr[dd], kk);
        sh[tid] = kk;
        __syncthreads();
        for (int off = 8; off > 0; off >>= 1) {
            if (ln < off) sh[tid] += sh[tid + off];
            __syncthreads();
        }
        if (ln == 0) keys[seq][st] = sh[tid];
        __syncthreads();
    }
    if (tid < NSEQ) {
        int ord[N_STEPS];
        for (int i = 0; i < N_STEPS; i++) ord[i] = i;
        for (int i = 1; i < N_STEPS; i++) {
            int oi = ord[i];
            float kv = keys[tid][oi];
            int j = i - 1;
            while (j >= 0 && keys[tid][ord[j]] > kv) { ord[j + 1] = ord[j]; j--; }
            ord[j + 1] = oi;
        }
        for (int i = 0; i < N_STEPS; i++) order[tid][i] = ord[i];
    }
    __syncthreads();
    float s = 0.0f;
    #pragma unroll
    for (int t = 0; t < 4; t++) {
        int idx = tid + t * 1024;
        int b  = idx >> 11;
        int st = (idx >> 7) & 15;
        int dd = idx & 127;
        float va = emb[((b    ) * N_STEPS + order[b    ][st]) * 128 + dd];
        float vb = emb[((2 + b) * N_STEPS + order[2 + b][st]) * 128 + dd];
        float df = va - vb;
        s = fmaf(df, df, s);
    }
    sh[tid] = s;
    __syncthreads();
    for (int off = 512; off > 0; off >>= 1) {
        if (tid < off) sh[tid] += sh[tid + off];
        __syncthreads();
    }
    if (tid == 0) {
        float mse = sh[0] / 4096.0f;
        float mad = 0.5f * (fabsf(norms[0] - norms[2]) + fabsf(norms[1] - norms[3]));
        out[0] = mse + mad;
    }
}

// ---------------------------------------------------------------------------
extern "C" void kernel_launch(void* const* d_in, const int* in_sizes, int n_in,
                              void* d_out, int out_size, void* d_ws, size_t ws_size,
                              hipStream_t stream) {
    const float* a    = (const float*)d_in[0];
    const float* b    = (const float*)d_in[1];
    const float* d    = (const float*)d_in[2];
    const float* ae   = (const float*)d_in[3];
    const float* proj = (const float*)d_in[4];
    float* out = (float*)d_out;

    float* ws  = (float*)d_ws;
    float* res = ws;                              // 65536 f
    float* du  = res + NSEQ * T_DIM;              // 16384 f
    float* emb = du + A_DIM * K_DIM;              // 8192 f
    unsigned long long* pmax  = (unsigned long long*)(emb + NSEQ * N_STEPS * 128); // 2048 u64
    unsigned long long* slots = pmax + NSEQ * NPT;                                 // 1920 u64
    int* cnt    = (int*)(slots + (N_STEPS - 1) * NSEQ * INC_B);
    int* dirty0 = cnt + NSEQ;                     // 8 ints

    k_prep<<<385, 256, 0, stream>>>(d, a, b, du, res, cnt, slots);

    dim3 gfull(NPT, NSEQ);
    k_step_full<<<gfull, 256, 0, stream>>>(res, du, ae, emb, pmax, cnt, dirty0);

    dim3 ginc(INC_B, NSEQ);
    k_inc<<<ginc, 256, 0, stream>>>(res, du, ae, emb, pmax, slots, dirty0);

    k_tail<<<1, 1024, 0, stream>>>(res, emb, proj, out);
}

// Round 11
// 235.086 us; speedup vs baseline: 1.3601x; 1.0372x over previous
//
#include <hip/hip_runtime.h>
#include <math.h>

#define T_DIM 16384
#define A_DIM 128
#define K_DIM 128
#define N_STEPS 16
#define E_DIM 126
#define NSEQ 4

// tiles: 16 atoms x 256 t -> 8 atiles x 64 ttiles = 512 tiles/seq
#define ATI 16
#define TT 256
#define NPT 512
#define NCB 32          // compute blocks/seq: 8 atiles x 2 halves x 2 parities
#define HB 8192         // half length in t
#define RL_LEN 8319     // local residual coverage: [base-64, base+8255]
#define RL_PAD 8608     // PIDX(8323)=8583 max touched; margin
#define SS_LEN 383      // staged window (step_full)
#define SS_PAD 404

#define PIDX(i) ((i) + ((i) >> 5))   // +1 pad per 32 dwords

// order-preserving pack: bigger u64 == (bigger value, then smaller flat idx).
// Never 0 for finite fm values -> 0 is the "empty mailbox" sentinel.
__device__ inline unsigned long long pack_vi(float v, int fi) {
    unsigned int b = __float_as_uint(v);
    b = (b & 0x80000000u) ? ~b : (b | 0x80000000u);
    return ((unsigned long long)b << 32) | (unsigned int)(~fi);
}
__device__ inline void unpack_vi(unsigned long long p, float* v, int* fi) {
    unsigned int lo = (unsigned int)(p & 0xffffffffu);
    unsigned int b = (unsigned int)(p >> 32);
    unsigned int fb = (b & 0x80000000u) ? (b & 0x7fffffffu) : ~b;
    *v = __uint_as_float(fb);
    *fi = (int)(~lo);
}

__device__ inline unsigned long long u64max(unsigned long long a, unsigned long long b) {
    return a > b ? a : b;
}

// ---------------------------------------------------------------------------
// blocks 0..127: d_unit rows; 128..383: res init; 384: zero cnt + mailboxes
__global__ __launch_bounds__(256) void k_prep(
    const float* __restrict__ d, const float* __restrict__ a,
    const float* __restrict__ b, float* __restrict__ du,
    float* __restrict__ res, int* __restrict__ cnt,
    unsigned long long* __restrict__ slots) {
    int blk = blockIdx.x, tid = threadIdx.x;
    if (blk < 128) {
        __shared__ float s[128];
        float v = 0.0f;
        if (tid < 128) { v = d[blk * K_DIM + tid]; s[tid] = v * v; }
        __syncthreads();
        for (int off = 64; off > 0; off >>= 1) {
            if (tid < off) s[tid] += s[tid + off];
            __syncthreads();
        }
        if (tid < 128) du[blk * K_DIM + tid] = v / (sqrtf(s[0]) + 1e-8f);
    } else if (blk < 384) {
        int i = (blk - 128) * 256 + tid;      // 0..65535
        res[i] = (i < 2 * T_DIM) ? a[i] : b[i - 2 * T_DIM];
    } else {
        if (tid < NSEQ) cnt[tid] = 0;
        // dslots 960 + wslots 60 = 1020 u64
        for (int i = tid; i < (N_STEPS - 1) * NSEQ * 16 + (N_STEPS - 1) * NSEQ;
             i += 256) slots[i] = 0ULL;
    }
}

// ---------------------------------------------------------------------------
// 16a x 256t tile engine (R10-proven). du via wave-uniform s_load float4;
// res via padded scalar b32 sliding window (zero conflicts). Per-acc FMA
// chain = k ascending -> bit-identical fm. Block argmax via shfl + red4.
__device__ inline unsigned long long tile_compute(
    const float* __restrict__ duP, const float* __restrict__ rsh,
    int L0, int a_lo, int t_lo, int tid, unsigned long long* red4) {

    float acc[4][4];
    #pragma unroll
    for (int i = 0; i < 4; i++)
        #pragma unroll
        for (int j = 0; j < 4; j++) acc[i][j] = 0.0f;

    float r[8];
    #pragma unroll
    for (int m = 0; m < 8; m++) r[m] = rsh[PIDX(L0 + m)];

    #pragma unroll 4
    for (int k = 0; k < K_DIM; k += 4) {
        float dA[4][4];
        #pragma unroll
        for (int i = 0; i < 4; i++)
            *(float4*)dA[i] = *(const float4*)(duP + i * K_DIM + k);  // uniform s_load
        #pragma unroll
        for (int dk = 0; dk < 4; dk++) {
            #pragma unroll
            for (int i = 0; i < 4; i++) {
                float s = dA[i][dk];
                #pragma unroll
                for (int j = 0; j < 4; j++)
                    acc[i][j] = fmaf(s, r[j + dk], acc[i][j]);   // k ascending per acc
            }
        }
        r[0] = r[4]; r[1] = r[5]; r[2] = r[6]; r[3] = r[7];
        #pragma unroll
        for (int m = 0; m < 4; m++) r[4 + m] = rsh[PIDX(L0 + k + 8 + m)];
    }

    float bv = -INFINITY;
    int bi = 0x7fffffff;
    #pragma unroll
    for (int i = 0; i < 4; i++) {          // ascending flat index scan
        int a = a_lo + i;
        #pragma unroll
        for (int j = 0; j < 4; j++) {
            int fi = a * T_DIM + t_lo + j;
            float v = acc[i][j];
            if (v > bv || (v == bv && fi < bi)) { bv = v; bi = fi; }
        }
    }
    #pragma unroll
    for (int off = 32; off > 0; off >>= 1) {
        float v2 = __shfl_down(bv, off);
        int   i2 = __shfl_down(bi, off);
        if (v2 > bv || (v2 == bv && i2 < bi)) { bv = v2; bi = i2; }
    }
    if ((tid & 63) == 0) red4[tid >> 6] = pack_vi(bv, bi);
    __syncthreads();
    if (tid == 0) {
        unsigned long long m = red4[0];
        #pragma unroll
        for (int w = 1; w < 4; w++) if (red4[w] > m) m = red4[w];
        red4[0] = m;
    }
    __syncthreads();
    return red4[0];
}

// ---------------------------------------------------------------------------
// step 0: 512 blocks/seq; staged padded window; last arrival reduces pmax,
// finalizes step 0 into global res/emb, publishes step-1 dirty window.
__global__ __launch_bounds__(256) void k_step_full(
    float* __restrict__ res, const float* __restrict__ du,
    const float* __restrict__ ae, float* __restrict__ emb,
    unsigned long long* __restrict__ pmax, int* __restrict__ cnt,
    int* __restrict__ dirty0) {

    int seq = blockIdx.y;
    int blk = blockIdx.x;                 // 0..511 = atile*64 + ttile
    int a_base = (blk >> 6) * ATI;
    int t0 = (blk & 63) * TT;
    int tid = threadIdx.x;

    __shared__ float rsh[SS_PAD];
    __shared__ unsigned long long red4[4];
    __shared__ unsigned long long pm_sh[256];
    __shared__ int last_flag;

    const float* resS = res + seq * T_DIM;
    for (int i = tid; i < SS_LEN; i += 256) {
        int t = t0 - 64 + i;
        rsh[PIDX(i)] = (t >= 0 && t < T_DIM) ? resS[t] : 0.0f;
    }
    __syncthreads();

    int tg = tid & 63;
    int ag = __builtin_amdgcn_readfirstlane(tid >> 6);
    unsigned long long p = tile_compute(du + (a_base + ag * 4) * K_DIM, rsh,
                                        4 * tg, a_base + ag * 4, t0 + 4 * tg,
                                        tid, red4);
    if (tid == 0) {
        pmax[seq * NPT + blk] = p;
        __threadfence();
        last_flag = (atomicAdd(&cnt[seq], 1) == NPT - 1);
    }
    __syncthreads();
    if (!last_flag) return;

    __threadfence();
    {
        unsigned long long m0 = pmax[seq * NPT + tid];
        unsigned long long m1 = pmax[seq * NPT + 256 + tid];
        pm_sh[tid] = u64max(m0, m1);
    }
    __syncthreads();
    for (int off = 128; off > 0; off >>= 1) {
        if (tid < off) pm_sh[tid] = u64max(pm_sh[tid], pm_sh[tid + off]);
        __syncthreads();
    }
    float value; int fi;
    unpack_vi(pm_sh[0], &value, &fi);
    int ai = fi >> 14;
    int ti = fi & (T_DIM - 1);
    int pos_idx = value > 0.0f ? ti : 0;
    int atom_idx = value > 0.0f ? ai : 0;

    float* e = emb + (seq * N_STEPS + 0) * 128;
    if (tid == 0) {
        e[0] = ((float)pos_idx / (float)(T_DIM - 1)) * 20.0f;
        e[1] = value;
        int nlo = ti - (K_DIM - 1); if (nlo < 0) nlo = 0;
        int nhi = ti + K_DIM;       if (nhi > T_DIM) nhi = T_DIM;
        dirty0[seq * 2 + 0] = nlo;
        dirty0[seq * 2 + 1] = nhi;
    }
    if (tid >= 2 && tid < 2 + E_DIM) e[tid] = ae[atom_idx * E_DIM + tid - 2];
    if (tid >= 128) {
        int k = tid - 128;
        int t = ti + k - K_DIM / 2;
        if (t >= 0 && t < T_DIM) {
            float r = res[seq * T_DIM + t];
            res[seq * T_DIM + t] = __fsub_rn(r, __fmul_rn(value, du[ai * K_DIM + k]));
        }
    }
}

// ---------------------------------------------------------------------------
// persistent steps 1..15. Coordinator-based protocol:
//  blk 0..31:  compute blocks (LDS-resident residual half). If dirty, compute
//              tile, atomicExch into per-(step,atile,ttile-idx) dslot. Then
//              ONE lane polls the per-(step,seq) winner slot (s_sleep backoff),
//              apply update locally, advance.
//  blk 32:     coordinator. 512-entry tile-max table in LDS; polls the <=16
//              expected dslots, updates table, reduces, writes emb row,
//              publishes winner u64.
__global__ __launch_bounds__(256) void k_inc(
    float* __restrict__ res, const float* __restrict__ du,
    const float* __restrict__ ae, float* __restrict__ emb,
    const unsigned long long* __restrict__ pmax,
    unsigned long long* __restrict__ dslots,
    unsigned long long* __restrict__ wslots, const int* __restrict__ dirty0) {

    int seq = blockIdx.y;
    int blk = blockIdx.x;                 // 0..32
    int tid = threadIdx.x;

    if (blk == NCB) {
        // ================= coordinator =================
        __shared__ unsigned long long table[NPT];     // 4 KB
        __shared__ unsigned long long red4[4];
        __shared__ unsigned long long wsh;
        for (int i = tid; i < NPT; i += 256) table[i] = pmax[seq * NPT + i];
        int lo = dirty0[seq * 2 + 0];
        int hi = dirty0[seq * 2 + 1];
        __syncthreads();

        for (int step = 1; step < N_STEPS; step++) {
            int T0 = lo >> 8, T1 = T0 + 1;
            bool hasT1 = (T1 < 64) && (T1 * TT < hi);
            if (tid < 16) {
                int a = tid >> 1, w = tid & 1;
                if (w == 0 || hasT1) {
                    const unsigned long long* sp =
                        &dslots[((step - 1) * NSEQ + seq) * 16 + tid];
                    unsigned long long v = __hip_atomic_load(sp, __ATOMIC_RELAXED,
                                                             __HIP_MEMORY_SCOPE_AGENT);
                    while (v == 0ULL) {
                        __builtin_amdgcn_s_sleep(1);
                        v = __hip_atomic_load(sp, __ATOMIC_RELAXED,
                                              __HIP_MEMORY_SCOPE_AGENT);
                    }
                    table[a * 64 + (w ? T1 : T0)] = v;
                }
            }
            __syncthreads();
            // reduce 512 -> winner
            unsigned long long m = u64max(table[tid], table[tid + 256]);
            #pragma unroll
            for (int off = 32; off > 0; off >>= 1)
                m = u64max(m, __shfl_down(m, off));
            if ((tid & 63) == 0) red4[tid >> 6] = m;
            __syncthreads();
            if (tid == 0) {
                unsigned long long w = red4[0];
                #pragma unroll
                for (int j = 1; j < 4; j++) w = u64max(w, red4[j]);
                wsh = w;
                atomicExch(&wslots[(step - 1) * NSEQ + seq], w);
            }
            __syncthreads();
            float value; int fi;
            unpack_vi(wsh, &value, &fi);
            int ti = fi & (T_DIM - 1);
            int ai = fi >> 14;
            int pos_idx = value > 0.0f ? ti : 0;
            int atom_idx = value > 0.0f ? ai : 0;
            float* e = emb + (seq * N_STEPS + step) * 128;
            if (tid == 0) {
                e[0] = ((float)pos_idx / (float)(T_DIM - 1)) * 20.0f;
                e[1] = value;
            }
            if (tid >= 2 && tid < 128) e[tid] = ae[atom_idx * E_DIM + tid - 2];
            lo = ti - (K_DIM - 1); if (lo < 0) lo = 0;
            hi = ti + K_DIM;       if (hi > T_DIM) hi = T_DIM;
        }
        return;
    }

    // ================= compute block =================
    int atile = blk >> 2;                 // 0..7
    int half = (blk >> 1) & 1;
    int par = blk & 1;
    int a_base = atile * ATI;
    int base = half * HB;

    __shared__ float resL[RL_PAD];             // ~34 KB padded local residual
    __shared__ unsigned long long red4[4];
    __shared__ unsigned long long wsh;

    const float* resG = res + seq * T_DIM;
    for (int i4 = tid * 4; i4 < RL_LEN; i4 += 1024) {
        int t = base - 64 + i4;
        if (t >= 0 && t + 3 < T_DIM && i4 + 3 < RL_LEN) {
            float4 v = *(const float4*)&resG[t];
            resL[PIDX(i4 + 0)] = v.x; resL[PIDX(i4 + 1)] = v.y;
            resL[PIDX(i4 + 2)] = v.z; resL[PIDX(i4 + 3)] = v.w;
        } else {
            for (int m = 0; m < 4 && i4 + m < RL_LEN; m++) {
                int t2 = t + m;
                resL[PIDX(i4 + m)] = (t2 >= 0 && t2 < T_DIM) ? resG[t2] : 0.0f;
            }
        }
    }
    int lo = dirty0[seq * 2 + 0];
    int hi = dirty0[seq * 2 + 1];
    __syncthreads();

    for (int step = 1; step < N_STEPS; step++) {
        int T0 = lo >> 8, T1 = T0 + 1;
        int cand = -1;
        if (((T0 & 1) == par) && ((T0 >> 5) == half)) cand = T0;
        else if (T1 < 64 && ((T1 & 1) == par) && ((T1 >> 5) == half) &&
                 T1 * TT < hi) cand = T1;

        if (cand >= 0) {
            int t0 = cand * TT;
            int tg = tid & 63;
            int ag = __builtin_amdgcn_readfirstlane(tid >> 6);
            unsigned long long p = tile_compute(
                du + (a_base + ag * 4) * K_DIM, resL,
                (t0 - base) + 4 * tg, a_base + ag * 4, t0 + 4 * tg, tid, red4);
            if (tid == 0)
                atomicExch(&dslots[((step - 1) * NSEQ + seq) * 16 +
                                   atile * 2 + (cand == T1 ? 1 : 0)], p);
        }
        // poll winner: one lane, one address, backoff
        if (tid == 0) {
            const unsigned long long* sp = &wslots[(step - 1) * NSEQ + seq];
            unsigned long long v = __hip_atomic_load(sp, __ATOMIC_RELAXED,
                                                     __HIP_MEMORY_SCOPE_AGENT);
            while (v == 0ULL) {
                __builtin_amdgcn_s_sleep(2);
                v = __hip_atomic_load(sp, __ATOMIC_RELAXED,
                                      __HIP_MEMORY_SCOPE_AGENT);
            }
            wsh = v;
        }
        __syncthreads();
        float value; int fi;
        unpack_vi(wsh, &value, &fi);
        int ti = fi & (T_DIM - 1);
        int ai = fi >> 14;
        // apply winner's update to local residual (mul-then-sub, step order)
        if (tid < 128) {
            int t = ti - K_DIM / 2 + tid;
            if (t >= 0 && t < T_DIM) {
                int L = t - base + 64;
                if (L >= 0 && L < RL_LEN) {
                    float r = resL[PIDX(L)];
                    resL[PIDX(L)] = __fsub_rn(r, __fmul_rn(value, du[ai * K_DIM + tid]));
                }
            }
        }
        __syncthreads();
        lo = ti - (K_DIM - 1); if (lo < 0) lo = 0;
        hi = ti + K_DIM;       if (hi > T_DIM) hi = T_DIM;
    }

    // final residual write-back (one block per half per seq) for k_tail
    if (atile == 0 && par == 0) {
        float* resW = res + seq * T_DIM + base;
        for (int t = tid; t < HB; t += 256) resW[t] = resL[PIDX(t + 64)];
    }
}

// ---------------------------------------------------------------------------
// norms + ordering + loss; 1 block x 1024 threads
__global__ __launch_bounds__(1024) void k_tail(
    const float* __restrict__ res, const float* __restrict__ emb,
    const float* __restrict__ proj, float* __restrict__ out) {
    int tid = threadIdx.x;
    __shared__ float sh[1024];
    __shared__ float norms[NSEQ];
    __shared__ float keys[NSEQ][N_STEPS];
    __shared__ int   order[NSEQ][N_STEPS];

    {
        int seq = tid >> 8;
        int ln  = tid & 255;
        const float4* r4 = (const float4*)(res + seq * T_DIM);
        float s = 0.0f;
        #pragma unroll
        for (int j = 0; j < 16; j++) {
            float4 v = r4[j * 256 + ln];
            s = fmaf(v.x, v.x, s); s = fmaf(v.y, v.y, s);
            s = fmaf(v.z, v.z, s); s = fmaf(v.w, v.w, s);
        }
        sh[tid] = s;
        __syncthreads();
        for (int off = 128; off > 0; off >>= 1) {
            if (ln < off) sh[tid] += sh[tid + off];
            __syncthreads();
        }
        if (ln == 0) norms[seq] = sqrtf(sh[tid]);
        __syncthreads();
    }
    {
        int pair = tid >> 4;
        int seq = pair >> 4, st = pair & 15;
        int ln = tid & 15;
        const float* e = emb + (seq * N_STEPS + st) * 128 + ln * 8;
        const float* pr = proj + ln * 8;
        float kk = 0.0f;
        #pragma unroll
        for (int dd = 0; dd < 8; dd++) kk = fmaf(e[dd], pr[dd], kk);
        sh[tid] = kk;
        __syncthreads();
        for (int off = 8; off > 0; off >>= 1) {
            if (ln < off) sh[tid] += sh[tid + off];
            __syncthreads();
        }
        if (ln == 0) keys[seq][st] = sh[tid];
        __syncthreads();
    }
    if (tid < NSEQ) {
        int ord[N_STEPS];
        for (int i = 0; i < N_STEPS; i++) ord[i] = i;
        for (int i = 1; i < N_STEPS; i++) {
            int oi = ord[i];
            float kv = keys[tid][oi];
            int j = i - 1;
            while (j >= 0 && keys[tid][ord[j]] > kv) { ord[j + 1] = ord[j]; j--; }
            ord[j + 1] = oi;
        }
        for (int i = 0; i < N_STEPS; i++) order[tid][i] = ord[i];
    }
    __syncthreads();
    float s = 0.0f;
    #pragma unroll
    for (int t = 0; t < 4; t++) {
        int idx = tid + t * 1024;
        int b  = idx >> 11;
        int st = (idx >> 7) & 15;
        int dd = idx & 127;
        float va = emb[((b    ) * N_STEPS + order[b    ][st]) * 128 + dd];
        float vb = emb[((2 + b) * N_STEPS + order[2 + b][st]) * 128 + dd];
        float df = va - vb;
        s = fmaf(df, df, s);
    }
    sh[tid] = s;
    __syncthreads();
    for (int off = 512; off > 0; off >>= 1) {
        if (tid < off) sh[tid] += sh[tid + off];
        __syncthreads();
    }
    if (tid == 0) {
        float mse = sh[0] / 4096.0f;
        float mad = 0.5f * (fabsf(norms[0] - norms[2]) + fabsf(norms[1] - norms[3]));
        out[0] = mse + mad;
    }
}

// ---------------------------------------------------------------------------
extern "C" void kernel_launch(void* const* d_in, const int* in_sizes, int n_in,
                              void* d_out, int out_size, void* d_ws, size_t ws_size,
                              hipStream_t stream) {
    const float* a    = (const float*)d_in[0];
    const float* b    = (const float*)d_in[1];
    const float* d    = (const float*)d_in[2];
    const float* ae   = (const float*)d_in[3];
    const float* proj = (const float*)d_in[4];
    float* out = (float*)d_out;

    float* ws  = (float*)d_ws;
    float* res = ws;                              // 65536 f
    float* du  = res + NSEQ * T_DIM;              // 16384 f
    float* emb = du + A_DIM * K_DIM;              // 8192 f
    unsigned long long* pmax   = (unsigned long long*)(emb + NSEQ * N_STEPS * 128); // 2048 u64
    unsigned long long* dslots = pmax + NSEQ * NPT;                    // 960 u64
    unsigned long long* wslots = dslots + (N_STEPS - 1) * NSEQ * 16;   // 60 u64
    int* cnt    = (int*)(wslots + (N_STEPS - 1) * NSEQ);
    int* dirty0 = cnt + NSEQ;                     // 8 ints

    k_prep<<<385, 256, 0, stream>>>(d, a, b, du, res, cnt, dslots);

    dim3 gfull(NPT, NSEQ);
    k_step_full<<<gfull, 256, 0, stream>>>(res, du, ae, emb, pmax, cnt, dirty0);

    dim3 ginc(NCB + 1, NSEQ);
    k_inc<<<ginc, 256, 0, stream>>>(res, du, ae, emb, pmax, dslots, wslots, dirty0);

    k_tail<<<1, 1024, 0, stream>>>(res, emb, proj, out);
}